// Round 3
// baseline (388.878 us; speedup 1.0000x reference)
//
#include <hip/hip_runtime.h>

#define NROWS 4
#define NBLK  2048
#define C1f 0.92387953251128674f
#define S1f 0.38268343236508978f
#define R2f 0.70710678118654752f
#define TWO_PI 6.28318530717958648f

// complex-index padding: +2 complex every 64 (keeps 16B alignment, breaks pow2 strides)
#define CIDX(c) ((c) + (((c) >> 6) << 1))

typedef float2 cf;

__device__ __forceinline__ cf cadd(cf a, cf b){ return make_float2(a.x+b.x, a.y+b.y); }
__device__ __forceinline__ cf csub(cf a, cf b){ return make_float2(a.x-b.x, a.y-b.y); }
__device__ __forceinline__ cf cmul(cf a, cf b){ return make_float2(a.x*b.x - a.y*b.y, a.x*b.y + a.y*b.x); }
__device__ __forceinline__ cf cmulNI(cf a){ return make_float2(a.y, -a.x); }              // * (-i)
__device__ __forceinline__ cf cW1(cf a){ return make_float2(C1f*a.x + S1f*a.y, C1f*a.y - S1f*a.x); }
__device__ __forceinline__ cf cW2(cf a){ return make_float2(R2f*(a.x + a.y), R2f*(a.y - a.x)); }
__device__ __forceinline__ cf cW3(cf a){ return make_float2(S1f*a.x + C1f*a.y, S1f*a.y - C1f*a.x); }
__device__ __forceinline__ cf cW6(cf a){ return make_float2(R2f*(a.y - a.x), -R2f*(a.x + a.y)); }
__device__ __forceinline__ cf cNW1(cf a){ return make_float2(-(C1f*a.x + S1f*a.y), S1f*a.x - C1f*a.y); }

// in-register 16-point DFT (natural in/out), radix-4 DIF
__device__ __forceinline__ void fft16(cf v[16]) {
    cf y[16];
    #pragma unroll
    for (int j1 = 0; j1 < 4; ++j1) {
        cf a0 = v[j1], a1 = v[j1+4], a2 = v[j1+8], a3 = v[j1+12];
        cf s0 = cadd(a0,a2), d0 = csub(a0,a2);
        cf s1 = cadd(a1,a3), d1 = csub(a1,a3);
        cf b0 = cadd(s0,s1);
        cf b1 = make_float2(d0.x + d1.y, d0.y - d1.x);
        cf b2 = csub(s0,s1);
        cf b3 = make_float2(d0.x - d1.y, d0.y + d1.x);
        if (j1 == 0)      { y[0]=b0; y[4]=b1;      y[8]=b2;          y[12]=b3; }
        else if (j1 == 1) { y[1]=b0; y[5]=cW1(b1); y[9]=cW2(b2);     y[13]=cW3(b3); }
        else if (j1 == 2) { y[2]=b0; y[6]=cW2(b1); y[10]=cmulNI(b2); y[14]=cW6(b3); }
        else              { y[3]=b0; y[7]=cW3(b1); y[11]=cW6(b2);    y[15]=cNW1(b3); }
    }
    #pragma unroll
    for (int p1 = 0; p1 < 4; ++p1) {
        cf c0 = y[4*p1], c1v = y[4*p1+1], c2v = y[4*p1+2], c3v = y[4*p1+3];
        cf s0 = cadd(c0,c2v), d0 = csub(c0,c2v);
        cf s1 = cadd(c1v,c3v), d1 = csub(c1v,c3v);
        v[p1]    = cadd(s0,s1);
        v[4+p1]  = make_float2(d0.x + d1.y, d0.y - d1.x);
        v[8+p1]  = csub(s0,s1);
        v[12+p1] = make_float2(d0.x - d1.y, d0.y + d1.x);
    }
}

// 64-lane sum via DPP; valid in lane 63
__device__ __forceinline__ float wred(float x) {
    x += __int_as_float(__builtin_amdgcn_update_dpp(0, __float_as_int(x), 0x111, 0xf, 0xf, false));
    x += __int_as_float(__builtin_amdgcn_update_dpp(0, __float_as_int(x), 0x112, 0xf, 0xf, false));
    x += __int_as_float(__builtin_amdgcn_update_dpp(0, __float_as_int(x), 0x114, 0xf, 0xf, false));
    x += __int_as_float(__builtin_amdgcn_update_dpp(0, __float_as_int(x), 0x118, 0xf, 0xf, false));
    x += __int_as_float(__builtin_amdgcn_update_dpp(0, __float_as_int(x), 0x142, 0xa, 0xf, false));
    x += __int_as_float(__builtin_amdgcn_update_dpp(0, __float_as_int(x), 0x143, 0xc, 0xf, false));
    return x;
}

// raw barrier: LDS-drain only; global prefetch loads stay in flight (vmcnt untouched)
__device__ __forceinline__ void bar_lds() {
    asm volatile("s_waitcnt lgkmcnt(0)" ::: "memory");
    __builtin_amdgcn_s_barrier();
    asm volatile("" ::: "memory");
}

__global__ __launch_bounds__(256, 4)
void fftmlp_r16p(const float* __restrict__ x, const float* __restrict__ w1,
                 const float* __restrict__ w2, float* __restrict__ out) {
    __shared__ cf lds[CIDX(4095) + 1];
    __shared__ float sred[40];
    const int t  = threadIdx.x;
    const int b0 = blockIdx.x * NROWS;
    const cf* __restrict__ w1c = (const cf*)w1;
    const cf* __restrict__ w2c = (const cf*)w2;

    // ---- prologue: all row-invariant values ----
    float sn, cs;
    __sincosf(-TWO_PI * (float)t * (1.0f/4096.0f), &sn, &cs);
    const cf wA = make_float2(cs, sn);                       // pass-A base twiddle
    __sincosf(-TWO_PI * (float)(t & 15) * (1.0f/256.0f), &sn, &cs);
    const cf wB = make_float2(cs, sn);                       // pass-B base twiddle
    const int c0i = ((t & 15) << 4) | (t >> 4);
    __sincosf(-TWO_PI * (float)c0i * (1.0f/1024.0f), &sn, &cs);
    const cf wk = make_float2(cs, sn);
    const cf r1 = wk;
    const cf r2 = cmul(r1, wk);
    const cf r3 = cmul(r2, wk);
    const cf r4 = cmul(r3, wk);
    const cf w2v0 = w2c[c0i], w2v1 = w2c[256 + c0i], w2v2 = w2c[512 + c0i], w2v3 = w2c[768 + c0i];

    // ---- prefetch row 0 ----
    cf P[16];
    {
        const cf* __restrict__ xr = (const cf*)x + (size_t)b0 * 4096;
        #pragma unroll
        for (int q = 0; q < 16; ++q) P[q] = xr[t + 256*q];
    }

    for (int rr = 0; rr < NROWS; ++rr) {
        // ---- consume prefetch, multiply by w1 (L2-hot reload) ----
        cf v[16];
        #pragma unroll
        for (int q = 0; q < 16; ++q) v[q] = cmul(P[q], w1c[t + 256*q]);
        // ---- issue next row's loads; they stay in flight across the barriers ----
        if (rr + 1 < NROWS) {
            const cf* __restrict__ xn = (const cf*)x + (size_t)(b0 + rr + 1) * 4096;
            #pragma unroll
            for (int q = 0; q < 16; ++q) P[q] = xn[t + 256*q];
        }

        // ---- pass A: 16-pt FFT over stride-256 columns, twiddle, -> LDS ----
        fft16(v);
        lds[CIDX(t)] = v[0];
        {
            cf tw = wA;
            #pragma unroll
            for (int p = 1; p < 16; ++p) {
                lds[CIDX(p*256 + t)] = cmul(v[p], tw);
                tw = cmul(tw, wA);
            }
        }
        bar_lds();

        // ---- pass B: 16-pt FFT over stride-16 within 256-blocks, twiddle, in place ----
        {
            const int p    = t >> 4;
            const int jp   = t & 15;
            const int base = p*256 + jp;
            cf u[16];
            #pragma unroll
            for (int q = 0; q < 16; ++q) u[q] = lds[CIDX(base + 16*q)];
            fft16(u);
            lds[CIDX(base)] = u[0];
            cf tw = wB;
            #pragma unroll
            for (int pp = 1; pp < 16; ++pp) {
                lds[CIDX(base + 16*pp)] = cmul(u[pp], tw);
                tw = cmul(tw, wB);
            }
        }
        bar_lds();

        // ---- final: 4 needed bins of 16-pt DFT + ReLU + w2 + 5-bin layer-2 DFT ----
        cf acc0, acc1, acc2, acc3, acc4;
        {
            cf z[16];
            const float4* __restrict__ lp = reinterpret_cast<const float4*>(&lds[CIDX(16*t)]);
            #pragma unroll
            for (int j2 = 0; j2 < 8; ++j2) {        // ds_read_b128 (contig + 16B aligned)
                float4 zv = lp[j2];
                z[2*j2]   = make_float2(zv.x, zv.y);
                z[2*j2+1] = make_float2(zv.z, zv.w);
            }
            cf A[4][4];
            #pragma unroll
            for (int bb = 0; bb < 4; ++bb) {
                cf a0 = z[bb], a1 = z[bb+4], a2 = z[bb+8], a3 = z[bb+12];
                cf s0 = cadd(a0,a2), d0 = csub(a0,a2);
                cf s1 = cadd(a1,a3), d1 = csub(a1,a3);
                A[bb][0] = cadd(s0,s1);
                A[bb][1] = make_float2(d0.x + d1.y, d0.y - d1.x);
                A[bb][2] = csub(s0,s1);
                A[bb][3] = make_float2(d0.x - d1.y, d0.y + d1.x);
            }
            cf F0 = cadd(cadd(A[0][0], A[1][0]),      cadd(A[2][0],      A[3][0]));
            cf F1 = cadd(cadd(A[0][1], cW1(A[1][1])), cadd(cW2(A[2][1]), cW3(A[3][1])));
            cf F2 = cadd(cadd(A[0][2], cW2(A[1][2])), cadd(cmulNI(A[2][2]), cW6(A[3][2])));
            cf F3 = cadd(cadd(A[0][3], cW3(A[1][3])), cadd(cW6(A[2][3]), cNW1(A[3][3])));

            cf h, P0, P1, P2, P3;
            h = make_float2(fmaxf(F0.x,0.f), fmaxf(F0.y,0.f)); P0 = cmul(h, w2v0);
            h = make_float2(fmaxf(F1.x,0.f), fmaxf(F1.y,0.f)); P1 = cmul(h, w2v1);
            h = make_float2(fmaxf(F2.x,0.f), fmaxf(F2.y,0.f)); P2 = cmul(h, w2v2);
            h = make_float2(fmaxf(F3.x,0.f), fmaxf(F3.y,0.f)); P3 = cmul(h, w2v3);

            cf s0 = cadd(P0,P2), d0 = csub(P0,P2);
            cf s1 = cadd(P1,P3), d1 = csub(P1,P3);
            cf G0 = cadd(s0,s1);
            cf G1 = make_float2(d0.x + d1.y, d0.y - d1.x);
            cf G2 = csub(s0,s1);
            cf G3 = make_float2(d0.x - d1.y, d0.y + d1.x);
            acc0 = G0;
            acc1 = cmul(G1, r1);
            acc2 = cmul(G2, r2);
            acc3 = cmul(G3, r3);
            acc4 = cmul(G0, r4);
        }

        // ---- reduce 256 threads -> 10 floats, store row ----
        float rv[10] = {acc0.x, acc0.y, acc1.x, acc1.y, acc2.x,
                        acc2.y, acc3.x, acc3.y, acc4.x, acc4.y};
        #pragma unroll
        for (int i = 0; i < 10; ++i) rv[i] = wred(rv[i]);
        const int lane = t & 63, wv = t >> 6;
        if (lane == 63) {
            #pragma unroll
            for (int i = 0; i < 10; ++i) sred[wv*10 + i] = rv[i];
        }
        bar_lds();   // also protects lds[] reuse by next row's pass A
        if (t < 10) {
            out[(size_t)(b0 + rr)*10 + t] = sred[t] + sred[10+t] + sred[20+t] + sred[30+t];
        }
    }
}

extern "C" void kernel_launch(void* const* d_in, const int* in_sizes, int n_in,
                              void* d_out, int out_size, void* d_ws, size_t ws_size,
                              hipStream_t stream) {
    const float* x  = (const float*)d_in[0];
    const float* w1 = (const float*)d_in[1];
    const float* w2 = (const float*)d_in[2];
    float* out = (float*)d_out;
    fftmlp_r16p<<<NBLK, 256, 0, stream>>>(x, w1, w2, out);
}

// Round 4
// 122.574 us; speedup vs baseline: 3.1726x; 3.1726x over previous
//
#include <hip/hip_runtime.h>
#include <stdint.h>

#define NROWS 8
#define NBLK  1024            // NBLK * NROWS = 8192 batch rows
#define C1f 0.92387953251128674f
#define S1f 0.38268343236508978f
#define R2f 0.70710678118654752f
#define TWO_PI 6.28318530717958648f

// work-buffer padding: +1 complex every 32 (R2-verified: all phases <=4-way, most 2-way)
#define CIDX(c) ((c) + ((c) >> 5))

typedef float2 cf;

__device__ __forceinline__ cf cadd(cf a, cf b){ return make_float2(a.x+b.x, a.y+b.y); }
__device__ __forceinline__ cf csub(cf a, cf b){ return make_float2(a.x-b.x, a.y-b.y); }
__device__ __forceinline__ cf cmul(cf a, cf b){ return make_float2(a.x*b.x - a.y*b.y, a.x*b.y + a.y*b.x); }
__device__ __forceinline__ cf cmulNI(cf a){ return make_float2(a.y, -a.x); }
__device__ __forceinline__ cf cW1(cf a){ return make_float2(C1f*a.x + S1f*a.y, C1f*a.y - S1f*a.x); }
__device__ __forceinline__ cf cW2(cf a){ return make_float2(R2f*(a.x + a.y), R2f*(a.y - a.x)); }
__device__ __forceinline__ cf cW3(cf a){ return make_float2(S1f*a.x + C1f*a.y, S1f*a.y - C1f*a.x); }
__device__ __forceinline__ cf cW6(cf a){ return make_float2(R2f*(a.y - a.x), -R2f*(a.x + a.y)); }
__device__ __forceinline__ cf cNW1(cf a){ return make_float2(-(C1f*a.x + S1f*a.y), S1f*a.x - C1f*a.y); }

// in-register 16-point DFT (natural in/out), radix-4 DIF
__device__ __forceinline__ void fft16(cf v[16]) {
    cf y[16];
    #pragma unroll
    for (int j1 = 0; j1 < 4; ++j1) {
        cf a0 = v[j1], a1 = v[j1+4], a2 = v[j1+8], a3 = v[j1+12];
        cf s0 = cadd(a0,a2), d0 = csub(a0,a2);
        cf s1 = cadd(a1,a3), d1 = csub(a1,a3);
        cf b0 = cadd(s0,s1);
        cf b1 = make_float2(d0.x + d1.y, d0.y - d1.x);
        cf b2 = csub(s0,s1);
        cf b3 = make_float2(d0.x - d1.y, d0.y + d1.x);
        if (j1 == 0)      { y[0]=b0; y[4]=b1;      y[8]=b2;          y[12]=b3; }
        else if (j1 == 1) { y[1]=b0; y[5]=cW1(b1); y[9]=cW2(b2);     y[13]=cW3(b3); }
        else if (j1 == 2) { y[2]=b0; y[6]=cW2(b1); y[10]=cmulNI(b2); y[14]=cW6(b3); }
        else              { y[3]=b0; y[7]=cW3(b1); y[11]=cW6(b2);    y[15]=cNW1(b3); }
    }
    #pragma unroll
    for (int p1 = 0; p1 < 4; ++p1) {
        cf c0 = y[4*p1], c1v = y[4*p1+1], c2v = y[4*p1+2], c3v = y[4*p1+3];
        cf s0 = cadd(c0,c2v), d0 = csub(c0,c2v);
        cf s1 = cadd(c1v,c3v), d1 = csub(c1v,c3v);
        v[p1]    = cadd(s0,s1);
        v[4+p1]  = make_float2(d0.x + d1.y, d0.y - d1.x);
        v[8+p1]  = csub(s0,s1);
        v[12+p1] = make_float2(d0.x - d1.y, d0.y + d1.x);
    }
}

// 64-lane sum via DPP; valid in lane 63
__device__ __forceinline__ float wred(float x) {
    x += __int_as_float(__builtin_amdgcn_update_dpp(0, __float_as_int(x), 0x111, 0xf, 0xf, false));
    x += __int_as_float(__builtin_amdgcn_update_dpp(0, __float_as_int(x), 0x112, 0xf, 0xf, false));
    x += __int_as_float(__builtin_amdgcn_update_dpp(0, __float_as_int(x), 0x114, 0xf, 0xf, false));
    x += __int_as_float(__builtin_amdgcn_update_dpp(0, __float_as_int(x), 0x118, 0xf, 0xf, false));
    x += __int_as_float(__builtin_amdgcn_update_dpp(0, __float_as_int(x), 0x142, 0xa, 0xf, false));
    x += __int_as_float(__builtin_amdgcn_update_dpp(0, __float_as_int(x), 0x143, 0xc, 0xf, false));
    return x;
}

// LDS-only barrier: global_load_lds prefetch stays in flight (vmcnt untouched)
__device__ __forceinline__ void bar_lds() {
    asm volatile("s_waitcnt lgkmcnt(0)" ::: "memory");
    __builtin_amdgcn_s_barrier();
}
// full drain barrier: prefetched row has landed in LDS
__device__ __forceinline__ void bar_vm() {
    asm volatile("s_waitcnt vmcnt(0) lgkmcnt(0)" ::: "memory");
    __builtin_amdgcn_s_barrier();
}

// stream one 32 KB x-row into LDS stage (linear layout), zero VGPR cost.
// wave w covers bytes [w*8192, (w+1)*8192): 8 calls x (64 lanes x 16 B).
__device__ __forceinline__ void load_row_to_stage(const cf* __restrict__ xrow,
                                                  cf* stage, int t) {
    const int lane = t & 63;
    const int woff = (t >> 6) * 8192;                 // bytes, wave-uniform
    const char* g = (const char*)xrow + woff + lane * 16;
    char* l = (char*)stage + woff;                    // lane part excluded (HW adds lane*16)
    #pragma unroll
    for (int k = 0; k < 8; ++k) {
        __builtin_amdgcn_global_load_lds(
            (const __attribute__((address_space(1))) uint32_t*)(g + k * 1024),
            (__attribute__((address_space(3))) uint32_t*)(l + k * 1024),
            16, 0, 0);
    }
}

__global__ __launch_bounds__(256, 2)
void fftmlp_r16s(const float* __restrict__ x, const float* __restrict__ w1,
                 const float* __restrict__ w2, float* __restrict__ out) {
    __shared__ __align__(16) cf stage[4096];          // 32 KB, linear (gload_lds dest)
    __shared__ cf work[CIDX(4095) + 1];               // ~33 KB, padded
    __shared__ float sred[40];
    const int t  = threadIdx.x;
    const int b0 = blockIdx.x * NROWS;
    const cf* __restrict__ w1c = (const cf*)w1;
    const cf* __restrict__ w2c = (const cf*)w2;
    const cf* __restrict__ xc  = (const cf*)x;

    // ---- issue row-0 stage load first; compute prologue while it flies ----
    load_row_to_stage(xc + (size_t)b0 * 4096, stage, t);

    float sn, cs;
    __sincosf(-TWO_PI * (float)t * (1.0f/4096.0f), &sn, &cs);
    const cf wA = make_float2(cs, sn);
    __sincosf(-TWO_PI * (float)(t & 15) * (1.0f/256.0f), &sn, &cs);
    const cf wB = make_float2(cs, sn);
    const int c0i = ((t & 15) << 4) | (t >> 4);
    __sincosf(-TWO_PI * (float)c0i * (1.0f/1024.0f), &sn, &cs);
    const cf wk = make_float2(cs, sn);
    const cf r1 = wk;
    const cf r2 = cmul(r1, wk);
    const cf r3 = cmul(r2, wk);
    const cf r4 = cmul(r3, wk);
    const cf w2v0 = w2c[c0i], w2v1 = w2c[256 + c0i], w2v2 = w2c[512 + c0i], w2v3 = w2c[768 + c0i];

    bar_vm();   // row 0 staged

    for (int rr = 0; rr < NROWS; ++rr) {
        // ---- pass A: stage (LDS) x w1 (L2) -> fft16 -> twiddle -> work ----
        cf v[16];
        #pragma unroll
        for (int q = 0; q < 16; ++q)
            v[q] = cmul(stage[t + 256*q], w1c[t + 256*q]);
        bar_lds();                                    // all waves done reading stage
        if (rr + 1 < NROWS)                           // stream next row; flies across barriers
            load_row_to_stage(xc + (size_t)(b0 + rr + 1) * 4096, stage, t);

        fft16(v);
        work[CIDX(t)] = v[0];
        {
            cf tw = wA;
            #pragma unroll
            for (int p = 1; p < 16; ++p) {
                work[CIDX(p*256 + t)] = cmul(v[p], tw);
                tw = cmul(tw, wA);
            }
        }
        bar_lds();

        // ---- pass B: 16-pt FFT over stride-16 within 256-blocks, twiddle, in place ----
        {
            const int p    = t >> 4;
            const int jp   = t & 15;
            const int base = p*256 + jp;
            cf u[16];
            #pragma unroll
            for (int q = 0; q < 16; ++q) u[q] = work[CIDX(base + 16*q)];
            fft16(u);
            work[CIDX(base)] = u[0];
            cf tw = wB;
            #pragma unroll
            for (int pp = 1; pp < 16; ++pp) {
                work[CIDX(base + 16*pp)] = cmul(u[pp], tw);
                tw = cmul(tw, wB);
            }
        }
        bar_lds();

        // ---- final: 4 needed bins of 16-pt DFT + ReLU + w2 + 5-bin layer-2 DFT ----
        cf acc0, acc1, acc2, acc3, acc4;
        {
            cf z[16];
            #pragma unroll
            for (int j = 0; j < 16; ++j) z[j] = work[CIDX(16*t + j)];
            cf A[4][4];
            #pragma unroll
            for (int bb = 0; bb < 4; ++bb) {
                cf a0 = z[bb], a1 = z[bb+4], a2 = z[bb+8], a3 = z[bb+12];
                cf s0 = cadd(a0,a2), d0 = csub(a0,a2);
                cf s1 = cadd(a1,a3), d1 = csub(a1,a3);
                A[bb][0] = cadd(s0,s1);
                A[bb][1] = make_float2(d0.x + d1.y, d0.y - d1.x);
                A[bb][2] = csub(s0,s1);
                A[bb][3] = make_float2(d0.x - d1.y, d0.y + d1.x);
            }
            cf F0 = cadd(cadd(A[0][0], A[1][0]),      cadd(A[2][0],      A[3][0]));
            cf F1 = cadd(cadd(A[0][1], cW1(A[1][1])), cadd(cW2(A[2][1]), cW3(A[3][1])));
            cf F2 = cadd(cadd(A[0][2], cW2(A[1][2])), cadd(cmulNI(A[2][2]), cW6(A[3][2])));
            cf F3 = cadd(cadd(A[0][3], cW3(A[1][3])), cadd(cW6(A[2][3]), cNW1(A[3][3])));

            cf h, P0, P1, P2, P3;
            h = make_float2(fmaxf(F0.x,0.f), fmaxf(F0.y,0.f)); P0 = cmul(h, w2v0);
            h = make_float2(fmaxf(F1.x,0.f), fmaxf(F1.y,0.f)); P1 = cmul(h, w2v1);
            h = make_float2(fmaxf(F2.x,0.f), fmaxf(F2.y,0.f)); P2 = cmul(h, w2v2);
            h = make_float2(fmaxf(F3.x,0.f), fmaxf(F3.y,0.f)); P3 = cmul(h, w2v3);

            cf s0 = cadd(P0,P2), d0 = csub(P0,P2);
            cf s1 = cadd(P1,P3), d1 = csub(P1,P3);
            cf G0 = cadd(s0,s1);
            cf G1 = make_float2(d0.x + d1.y, d0.y - d1.x);
            cf G2 = csub(s0,s1);
            cf G3 = make_float2(d0.x - d1.y, d0.y + d1.x);
            acc0 = G0;
            acc1 = cmul(G1, r1);
            acc2 = cmul(G2, r2);
            acc3 = cmul(G3, r3);
            acc4 = cmul(G0, r4);
        }

        // ---- reduce 256 threads -> 10 floats, store row ----
        float rv[10] = {acc0.x, acc0.y, acc1.x, acc1.y, acc2.x,
                        acc2.y, acc3.x, acc3.y, acc4.x, acc4.y};
        #pragma unroll
        for (int i = 0; i < 10; ++i) rv[i] = wred(rv[i]);
        const int lane = t & 63, wv = t >> 6;
        if (lane == 63) {
            #pragma unroll
            for (int i = 0; i < 10; ++i) sred[wv*10 + i] = rv[i];
        }
        bar_lds();
        if (t < 10) {
            out[(b0 + rr)*10 + t] = sred[t] + sred[10+t] + sred[20+t] + sred[30+t];
        }
        bar_vm();   // next row staged + sred consumed before reuse
    }
}

extern "C" void kernel_launch(void* const* d_in, const int* in_sizes, int n_in,
                              void* d_out, int out_size, void* d_ws, size_t ws_size,
                              hipStream_t stream) {
    const float* x  = (const float*)d_in[0];
    const float* w1 = (const float*)d_in[1];
    const float* w2 = (const float*)d_in[2];
    float* out = (float*)d_out;
    fftmlp_r16s<<<NBLK, 256, 0, stream>>>(x, w1, w2, out);
}